// Round 1
// baseline (546.051 us; speedup 1.0000x reference)
//
#include <hip/hip_runtime.h>
#include <cstdint>
#include <cstddef>

typedef __attribute__((ext_vector_type(4))) float f32x4;
typedef __attribute__((ext_vector_type(8))) short bf16x8;

#define S_LEN 2048
#define HDIM 4096
#define QKVD 6144
#define NHEAD 32
#define NKVH 8
#define HD 128
#define ATT_SCALE 0.08838834764831845f

// fp32 -> bf16 RNE (finite inputs only)
__device__ __forceinline__ short f2bf(float f) {
  unsigned int u = __float_as_uint(f);
  u += 0x7FFFu + ((u >> 16) & 1u);
  return (short)(u >> 16);
}

__global__ void cvt_kernel(const float* __restrict__ in, short* __restrict__ out, int n) {
  int i = (blockIdx.x * blockDim.x + threadIdx.x) * 4;
  if (i >= n) return;
  const float4 v = *reinterpret_cast<const float4*>(in + i);
  short4 o;
  o.x = f2bf(v.x); o.y = f2bf(v.y); o.z = f2bf(v.z); o.w = f2bf(v.w);
  *reinterpret_cast<short4*>(out + i) = o;
}

// C[M][N] = A[M][K] * B[N][K]^T   (bf16 in, fp32 out), 128x128 tile, BK=32
__global__ __launch_bounds__(256) void gemm_bt(const short* __restrict__ A,
                                               const short* __restrict__ B,
                                               float* __restrict__ C,
                                               int M, int N, int K) {
  __shared__ short lA[128 * 32];
  __shared__ short lB[128 * 32];
  const int t = threadIdx.x;
  const int w = t >> 6, lane = t & 63;
  const int l15 = lane & 15, l4 = lane >> 4;
  const int tm = blockIdx.y * 128, tn = blockIdx.x * 128;
  const int wr = (w >> 1) * 64, wc = (w & 1) * 64;

  // staging: 512 chunks of 8 bf16; thread t owns chunks {t, t+256}
  const int r0 = t >> 2, cc0 = (t & 3) * 8;
  const int r1 = (t + 256) >> 2;
  const short* gA0 = A + (size_t)(tm + r0) * K + cc0;
  const short* gA1 = A + (size_t)(tm + r1) * K + cc0;
  const short* gB0 = B + (size_t)(tn + r0) * K + cc0;
  const short* gB1 = B + (size_t)(tn + r1) * K + cc0;

  f32x4 acc[4][4] = {};

  bf16x8 sa0 = *reinterpret_cast<const bf16x8*>(gA0);
  bf16x8 sa1 = *reinterpret_cast<const bf16x8*>(gA1);
  bf16x8 sb0 = *reinterpret_cast<const bf16x8*>(gB0);
  bf16x8 sb1 = *reinterpret_cast<const bf16x8*>(gB1);

  for (int k0 = 0; k0 < K; k0 += 32) {
    *reinterpret_cast<bf16x8*>(lA + t * 8) = sa0;
    *reinterpret_cast<bf16x8*>(lA + (t + 256) * 8) = sa1;
    *reinterpret_cast<bf16x8*>(lB + t * 8) = sb0;
    *reinterpret_cast<bf16x8*>(lB + (t + 256) * 8) = sb1;
    __syncthreads();
    if (k0 + 32 < K) {  // prefetch next K-tile into regs, overlaps MFMAs below
      sa0 = *reinterpret_cast<const bf16x8*>(gA0 + k0 + 32);
      sa1 = *reinterpret_cast<const bf16x8*>(gA1 + k0 + 32);
      sb0 = *reinterpret_cast<const bf16x8*>(gB0 + k0 + 32);
      sb1 = *reinterpret_cast<const bf16x8*>(gB1 + k0 + 32);
    }
    bf16x8 af[4], bfr[4];
#pragma unroll
    for (int m = 0; m < 4; ++m)
      af[m] = *reinterpret_cast<const bf16x8*>(lA + (wr + m * 16 + l15) * 32 + l4 * 8);
#pragma unroll
    for (int n = 0; n < 4; ++n)
      bfr[n] = *reinterpret_cast<const bf16x8*>(lB + (wc + n * 16 + l15) * 32 + l4 * 8);
#pragma unroll
    for (int m = 0; m < 4; ++m)
#pragma unroll
      for (int n = 0; n < 4; ++n)
        acc[m][n] = __builtin_amdgcn_mfma_f32_16x16x32_bf16(af[m], bfr[n], acc[m][n], 0, 0, 0);
    __syncthreads();
  }
#pragma unroll
  for (int m = 0; m < 4; ++m)
#pragma unroll
    for (int n = 0; n < 4; ++n)
#pragma unroll
      for (int r = 0; r < 4; ++r) {
        int rr = tm + wr + m * 16 + l4 * 4 + r;
        int cc = tn + wc + n * 16 + l15;
        C[(size_t)rr * N + cc] = acc[m][n][r];
      }
}

// qkv fp32 [S][6144] -> roped bf16 Q[NH][S][HD], K[NKV][S][HD], V[NKV][S][HD]
__global__ void rope_kernel(const float* __restrict__ qkv,
                            const float* __restrict__ cb,
                            const float* __restrict__ sb,
                            short* __restrict__ Q,
                            short* __restrict__ Kx,
                            short* __restrict__ V) {
  int tid = blockIdx.x * blockDim.x + threadIdx.x;
  int s = tid / QKVD;
  int j = tid - s * QKVD;
  int g = j / 768;
  int idx = j - g * 768;
  float val = qkv[tid];
  if (idx < 640) {
    int part = idx >> 7;  // 0..3 = q heads in group, 4 = k
    int d = idx & 127;
    int d2 = (d < 64) ? d + 64 : d - 64;
    float pv = qkv[(size_t)s * QKVD + g * 768 + part * 128 + d2];
    float c = cb[s * HD + d], sn = sb[s * HD + d];
    float ov = (d < 64) ? (val * c - pv * sn) : (val * c + pv * sn);
    if (part < 4) {
      int hh = g * 4 + part;
      Q[((size_t)hh * S_LEN + s) * HD + d] = f2bf(ov);
    } else {
      Kx[((size_t)g * S_LEN + s) * HD + d] = f2bf(ov);
    }
  } else {
    int d = idx - 640;
    V[((size_t)g * S_LEN + s) * HD + d] = f2bf(val);
  }
}

// flash attention: 1 wave per (head, 16-row q tile); KV tiles of 32
__global__ __launch_bounds__(64) void attn_kernel(const short* __restrict__ Q,
                                                  const short* __restrict__ Kx,
                                                  const short* __restrict__ V,
                                                  short* __restrict__ AO) {
  __shared__ short lVt[HD * 32];  // V^T [d][kv]
  __shared__ short lP[16 * 32];   // P [q][kv]
  const int h = blockIdx.x, qt = blockIdx.y;
  const int kvh = h >> 2;
  const int lane = threadIdx.x;
  const int l15 = lane & 15, l4 = lane >> 4;

  bf16x8 qf[4];
  const short* qrow = Q + ((size_t)h * S_LEN + qt * 16 + l15) * HD + l4 * 8;
#pragma unroll
  for (int fd = 0; fd < 4; ++fd)
    qf[fd] = *reinterpret_cast<const bf16x8*>(qrow + fd * 32);

  f32x4 o[8] = {};
  float m_run[4] = {-1e30f, -1e30f, -1e30f, -1e30f};
  float lsum[4] = {0.f, 0.f, 0.f, 0.f};

  const short* Kb = Kx + (size_t)kvh * S_LEN * HD;
  const short* Vb = V + (size_t)kvh * S_LEN * HD;
  const int nkt = ((qt * 16 + 15) >> 5) + 1;

  for (int kt = 0; kt < nkt; ++kt) {
    const int c0 = kt * 32;
    {  // stage V^T into LDS: lane covers row (lane>>1), 64-col half (lane&1)
      const short* vrow = Vb + (size_t)(c0 + (lane >> 1)) * HD + (lane & 1) * 64;
      const int r = lane >> 1, cb2 = (lane & 1) * 64;
#pragma unroll
      for (int i = 0; i < 8; ++i) {
        bf16x8 vv = *reinterpret_cast<const bf16x8*>(vrow + i * 8);
#pragma unroll
        for (int jj = 0; jj < 8; ++jj)
          lVt[(cb2 + i * 8 + jj) * 32 + r] = vv[jj];
      }
    }
    // QK^T: S[16q][32kv]
    f32x4 sf[2] = {};
#pragma unroll
    for (int n = 0; n < 2; ++n) {
      const short* krow = Kb + (size_t)(c0 + n * 16 + l15) * HD + l4 * 8;
#pragma unroll
      for (int fd = 0; fd < 4; ++fd) {
        bf16x8 kf = *reinterpret_cast<const bf16x8*>(krow + fd * 32);
        sf[n] = __builtin_amdgcn_mfma_f32_16x16x32_bf16(qf[fd], kf, sf[n], 0, 0, 0);
      }
    }
    const bool msk = (c0 + 31) > qt * 16;  // only last tile straddles diagonal
#pragma unroll
    for (int n = 0; n < 2; ++n)
#pragma unroll
      for (int r = 0; r < 4; ++r) {
        float v = sf[n][r] * ATT_SCALE;
        if (msk && (c0 + n * 16 + l15) > (qt * 16 + l4 * 4 + r)) v = -1e30f;
        sf[n][r] = v;
      }
    float alpha[4];
#pragma unroll
    for (int r = 0; r < 4; ++r) {
      float mx = fmaxf(sf[0][r], sf[1][r]);
      mx = fmaxf(mx, __shfl_xor(mx, 1, 64));
      mx = fmaxf(mx, __shfl_xor(mx, 2, 64));
      mx = fmaxf(mx, __shfl_xor(mx, 4, 64));
      mx = fmaxf(mx, __shfl_xor(mx, 8, 64));
      float mnew = fmaxf(m_run[r], mx);
      alpha[r] = __expf(m_run[r] - mnew);
      m_run[r] = mnew;
      sf[0][r] = __expf(sf[0][r] - mnew);
      sf[1][r] = __expf(sf[1][r] - mnew);
      float sum = sf[0][r] + sf[1][r];
      sum += __shfl_xor(sum, 1, 64);
      sum += __shfl_xor(sum, 2, 64);
      sum += __shfl_xor(sum, 4, 64);
      sum += __shfl_xor(sum, 8, 64);
      lsum[r] = lsum[r] * alpha[r] + sum;
    }
#pragma unroll
    for (int fd = 0; fd < 8; ++fd) {
      o[fd][0] *= alpha[0]; o[fd][1] *= alpha[1];
      o[fd][2] *= alpha[2]; o[fd][3] *= alpha[3];
    }
#pragma unroll
    for (int n = 0; n < 2; ++n)
#pragma unroll
      for (int r = 0; r < 4; ++r)
        lP[(l4 * 4 + r) * 32 + n * 16 + l15] = f2bf(sf[n][r]);
    __syncthreads();
    // PV: O[16q][128d] += P[16q][32kv] * V[32kv][128d]
    bf16x8 pf = *reinterpret_cast<const bf16x8*>(lP + l15 * 32 + l4 * 8);
#pragma unroll
    for (int fd = 0; fd < 8; ++fd) {
      bf16x8 vf = *reinterpret_cast<const bf16x8*>(lVt + (fd * 16 + l15) * 32 + l4 * 8);
      o[fd] = __builtin_amdgcn_mfma_f32_16x16x32_bf16(pf, vf, o[fd], 0, 0, 0);
    }
    __syncthreads();
  }
  float inv[4];
#pragma unroll
  for (int r = 0; r < 4; ++r) inv[r] = 1.f / lsum[r];
#pragma unroll
  for (int fd = 0; fd < 8; ++fd)
#pragma unroll
    for (int r = 0; r < 4; ++r)
      AO[(size_t)(qt * 16 + l4 * 4 + r) * HDIM + h * HD + fd * 16 + l15] =
          f2bf(o[fd][r] * inv[r]);
}

extern "C" void kernel_launch(void* const* d_in, const int* in_sizes, int n_in,
                              void* d_out, int out_size, void* d_ws, size_t ws_size,
                              hipStream_t stream) {
  const float* hidden = (const float*)d_in[0];
  const float* w_attn = (const float*)d_in[1];
  const float* w_proj = (const float*)d_in[2];
  const float* rcos = (const float*)d_in[3];
  const float* rsin = (const float*)d_in[4];
  float* out = (float*)d_out;
  char* ws = (char*)d_ws;

  // workspace layout (112 MiB total, overlaid):
  //  [0,16Mi)    Xb (bf16 X)          -> reused as AO after gemm1
  //  [16,64Mi)   Wab (bf16 w_attn)    -> reused as Qb[16,32) Kb[32,36) Vb[36,40) after gemm1
  //  [64,112Mi)  QKVf (fp32 qkv)      -> reused as Wpb (bf16 w_proj) after rope
  short* Xb  = (short*)(ws);
  short* Wab = (short*)(ws + (16u << 20));
  short* Qb  = (short*)(ws + (16u << 20));
  short* Kb  = (short*)(ws + (32u << 20));
  short* Vb  = (short*)(ws + (36u << 20));
  float* QKVf = (float*)(ws + (64u << 20));
  short* Wpb = (short*)(ws + (64u << 20));
  short* AO  = Xb;

  const int nX = S_LEN * HDIM;       // 8388608
  const int nWa = QKVD * HDIM;       // 25165824
  const int nWp = HDIM * HDIM;       // 16777216

  cvt_kernel<<<nX / 1024, 256, 0, stream>>>(hidden, Xb, nX);
  cvt_kernel<<<nWa / 1024, 256, 0, stream>>>(w_attn, Wab, nWa);
  gemm_bt<<<dim3(QKVD / 128, S_LEN / 128), 256, 0, stream>>>(Xb, Wab, QKVf, S_LEN, QKVD, HDIM);
  rope_kernel<<<(S_LEN * QKVD) / 256, 256, 0, stream>>>(QKVf, rcos, rsin, Qb, Kb, Vb);
  cvt_kernel<<<nWp / 1024, 256, 0, stream>>>(w_proj, Wpb, nWp);
  attn_kernel<<<dim3(NHEAD, S_LEN / 16), 64, 0, stream>>>(Qb, Kb, Vb, AO);
  gemm_bt<<<dim3(HDIM / 128, S_LEN / 128), 256, 0, stream>>>(AO, Wpb, out, S_LEN, HDIM, HDIM);
}